// Round 4
// baseline (94.209 us; speedup 1.0000x reference)
//
#include <hip/hip_runtime.h>

#define BB 4
#define CC 32
#define HH 512
#define WW 512
#define TS 16   // 16x16 pixel tile per 256-thread block

// 8-byte vector load with only 4-byte alignment guarantee (x0 may be odd).
typedef float f2v __attribute__((ext_vector_type(2), aligned(4)));

__global__ __launch_bounds__(256) void warp_bilinear_kernel(
    const float* __restrict__ src,
    const float* __restrict__ flow,
    float* __restrict__ out)
{
    const int HW = HH * WW;

    // Bijective XCD swizzle (gridDim.x == 4096, divisible by 8).
    int nper = gridDim.x >> 3;
    int bid = (blockIdx.x & 7) * nper + (blockIdx.x >> 3);

    // Tile decomposition: bid -> (b, tile-y, tile-x). 32x32 tiles per image.
    int b  = bid >> 10;           // 1024 tiles per batch image
    int ty = (bid >> 5) & 31;
    int tx = bid & 31;

    // 2D lane mapping: wave covers a 16x4 patch -> per-gather cache-line
    // footprint ~31 lines vs ~50 for 64x1; block footprint/channel ~2.4 KB
    // so halo re-reads across the block's 4 waves hit L1.
    int lx = threadIdx.x & (TS - 1);
    int ly = threadIdx.x >> 4;

    int h = ty * TS + ly;
    int w = tx * TS + lx;
    int p = h * WW + w;

    // flow channel 0 = y offset, channel 1 = x offset (streamed once -> nt)
    float fy = __builtin_nontemporal_load(flow + (b * 2 + 0) * HW + p);
    float fx = __builtin_nontemporal_load(flow + (b * 2 + 1) * HW + p);

    float y = fminf(fmaxf((float)h + fy, 0.0f), (float)(HH - 1));
    float x = fminf(fmaxf((float)w + fx, 0.0f), (float)(WW - 1));

    // Border fold: x0 = min(floor(x), W-2), wx = x - x0 reproduces the
    // reference (floor + clamped neighbor) exactly; guarantees x1 == x0+1,
    // so each row-tap is ONE float2 load.
    int y0 = min((int)floorf(y), HH - 2);
    int x0 = min((int)floorf(x), WW - 2);
    float wy = y - (float)y0;
    float wx = x - (float)x0;

    float w00 = (1.0f - wy) * (1.0f - wx);
    float w01 = (1.0f - wy) * wx;
    float w10 = wy * (1.0f - wx);
    float w11 = wy * wx;

    int i0 = y0 * WW + x0;        // top-left  (covers x0, x0+1)
    int i1 = i0 + WW;             // bottom-left

    const float* sb = src + (size_t)b * CC * HW;
    float*       ob = out + (size_t)b * CC * HW;

    // 8 channels per batch: 16 dwordx2 gathers in flight -> hide L2/L3 latency.
    #pragma unroll
    for (int c0 = 0; c0 < CC; c0 += 8) {
        f2v t[8], bt[8];
        #pragma unroll
        for (int k = 0; k < 8; ++k) {
            const float* s = sb + (c0 + k) * HW;
            t[k]  = *(const f2v*)(s + i0);
            bt[k] = *(const f2v*)(s + i1);
        }
        #pragma unroll
        for (int k = 0; k < 8; ++k) {
            float v = t[k].x * w00 + t[k].y * w01
                    + bt[k].x * w10 + bt[k].y * w11;
            __builtin_nontemporal_store(v, ob + (c0 + k) * HW + p);
        }
    }
}

extern "C" void kernel_launch(void* const* d_in, const int* in_sizes, int n_in,
                              void* d_out, int out_size, void* d_ws, size_t ws_size,
                              hipStream_t stream) {
    const float* src  = (const float*)d_in[0];
    const float* flow = (const float*)d_in[1];
    float* out = (float*)d_out;

    const int nblocks = BB * (HH / TS) * (WW / TS);   // 4096, divisible by 8
    warp_bilinear_kernel<<<nblocks, 256, 0, stream>>>(src, flow, out);
}

// Round 5
// 86.318 us; speedup vs baseline: 1.0914x; 1.0914x over previous
//
#include <hip/hip_runtime.h>

#define BB 4
#define CC 32
#define HH 512
#define WW 512
#define TS 16          // 16x16 output tile per 256-thread block
#define SH 25          // staged rows:  [ty*16-4, ty*16+20]  (halo -4 / +5 incl. y1)
#define SW 32          // staged cols:  [tx*16-4, tx*16+27]  (pow2 for cheap addressing)
#define CH_BATCH 8
#define CSTRIDE (SH * SW)   // 800 floats per channel

// 16-byte vector load with only 4-byte alignment guarantee.
typedef float f4v __attribute__((ext_vector_type(4), aligned(4)));

__global__ __launch_bounds__(256) void warp_bilinear_kernel(
    const float* __restrict__ src,
    const float* __restrict__ flow,
    float* __restrict__ out)
{
    const int HW = HH * WW;
    __shared__ float smem[CH_BATCH * CSTRIDE];   // 25.6 KB -> 6 blocks/CU

    // Bijective XCD swizzle (gridDim.x == 4096, divisible by 8).
    int nper = gridDim.x >> 3;
    int bid = (blockIdx.x & 7) * nper + (blockIdx.x >> 3);

    // bid -> (b, tile-y, tile-x); 32x32 tiles per image.
    int b  = bid >> 10;
    int ty = (bid >> 5) & 31;
    int tx = bid & 31;

    int tid  = threadIdx.x;
    int lane = tid & 63;
    int wv   = tid >> 6;        // wave id 0..3
    int lx   = tid & (TS - 1);
    int ly   = tid >> 4;

    int h = ty * TS + ly;
    int w = tx * TS + lx;
    int p = h * WW + w;

    int row_base = ty * TS - 4;
    int col_base = tx * TS - 4;

    const float* sb = src + (size_t)b * CC * HW;
    float*       ob = out + (size_t)b * CC * HW;

    // flow: ch0 = y offset, ch1 = x offset (streamed once -> nt)
    float fy = __builtin_nontemporal_load(flow + (b * 2 + 0) * HW + p);
    float fx = __builtin_nontemporal_load(flow + (b * 2 + 1) * HW + p);

    float y = fminf(fmaxf((float)h + fy, 0.0f), (float)(HH - 1));
    float x = fminf(fmaxf((float)w + fx, 0.0f), (float)(WW - 1));

    // Border fold: x0 = min(floor(x), W-2), wx = x - x0 == reference exactly
    // (at x == W-1 the left tap weight becomes exactly 0). Guarantees
    // x1 == x0+1, y1 == y0+1.
    int y0 = min((int)floorf(y), HH - 2);
    int x0 = min((int)floorf(x), WW - 2);
    float wy = y - (float)y0;
    float wx = x - (float)x0;

    float w00 = (1.0f - wy) * (1.0f - wx);
    float w01 = (1.0f - wy) * wx;
    float w10 = wy * (1.0f - wx);
    float w11 = wy * wx;

    int r0 = y0 - row_base;          // staged-tile coords
    int c0 = x0 - col_base;
    bool in_tile = ((unsigned)r0 <= (SH - 2)) && ((unsigned)c0 <= (SW - 2));
    int lbase = r0 * SW + c0;        // LDS offset within a channel slab

    int i0 = y0 * WW + x0;           // global fallback indices
    int i1 = i0 + WW;

    // Col range identity (no clamp needed) for interior-x tiles.
    bool interior_x = (col_base >= 0) && (col_base + SW <= WW);

    for (int cb = 0; cb < 4; ++cb) {
        __syncthreads();             // previous batch's LDS reads done

        // ---- stage CH_BATCH channels; wave wv owns channels wv*2, wv*2+1 ----
        int ch0 = cb * CH_BATCH + (wv << 1);
        if (interior_x) {
            #pragma unroll
            for (int rep = 0; rep < 2; ++rep) {
                const float* s = sb + (ch0 + rep) * HW;
                float* dst = smem + ((wv << 1) + rep) * CSTRIDE;
                #pragma unroll
                for (int it = 0; it < 4; ++it) {
                    int e = lane + it * 64;          // x4-element index, 200 total
                    if (e < CSTRIDE / 4) {
                        int e4 = e << 2;
                        int r = e4 >> 5;             // SW == 32
                        int srow = min(max(row_base + r, 0), HH - 1);
                        f4v v = *(const f4v*)(s + srow * WW + col_base + (e4 & 31));
                        *(f4v*)(dst + e4) = v;       // r*SW + c == e4
                    }
                }
            }
        } else {
            #pragma unroll
            for (int rep = 0; rep < 2; ++rep) {
                const float* s = sb + (ch0 + rep) * HW;
                float* dst = smem + ((wv << 1) + rep) * CSTRIDE;
                for (int e = lane; e < CSTRIDE; e += 64) {
                    int r = e >> 5, c = e & 31;
                    int srow = min(max(row_base + r, 0), HH - 1);
                    int scol = min(max(col_base + c, 0), WW - 1);
                    dst[e] = s[srow * WW + scol];
                }
            }
        }
        __syncthreads();

        // ---- compute: 4 LDS taps per channel (rare out-of-halo -> global) ----
        if (in_tile) {
            #pragma unroll
            for (int k = 0; k < CH_BATCH; ++k) {
                const float* ls = smem + k * CSTRIDE + lbase;
                float v = ls[0]  * w00 + ls[1]      * w01
                        + ls[SW] * w10 + ls[SW + 1] * w11;
                __builtin_nontemporal_store(v, ob + (cb * CH_BATCH + k) * HW + p);
            }
        } else {
            #pragma unroll
            for (int k = 0; k < CH_BATCH; ++k) {
                const float* s = sb + (cb * CH_BATCH + k) * HW;
                float v = s[i0] * w00 + s[i0 + 1] * w01
                        + s[i1] * w10 + s[i1 + 1] * w11;
                __builtin_nontemporal_store(v, ob + (cb * CH_BATCH + k) * HW + p);
            }
        }
    }
}

extern "C" void kernel_launch(void* const* d_in, const int* in_sizes, int n_in,
                              void* d_out, int out_size, void* d_ws, size_t ws_size,
                              hipStream_t stream) {
    const float* src  = (const float*)d_in[0];
    const float* flow = (const float*)d_in[1];
    float* out = (float*)d_out;

    const int nblocks = BB * (HH / TS) * (WW / TS);   // 4096, divisible by 8
    warp_bilinear_kernel<<<nblocks, 256, 0, stream>>>(src, flow, out);
}